// Round 2
// baseline (415.532 us; speedup 1.0000x reference)
//
#include <hip/hip_runtime.h>

// network_5299989643808: per-(z,zp) tiny MLP over B observations.
// B=2048, Z=64, IDIM=2, HDIM=4, NOPT=4. f32 in / f32 out.
// Outputs concat flat: pi [B,Z,Z,4], log_pi [B,Z,Z,4], xi [B,Z,Z,4].
//
// R2: occupancy fix. R1 held 88 weight floats + unroll-2 temps live across
// the whole b-loop (~150 VGPR -> 2 waves/SIMD tier, latency-bound at ~156us
// vs ~64us write floor). Split into two phases so weight liveness never
// overlaps:
//   phase 1 (trunk: W1,b1,g1,be1,W2,b2,g2,be2 = 48 regs) -> h2s[8][4]
//   phase 2 (heads: Wpi,bpi,Wxi,bxi = 40 regs) reads h2s, stores outputs
// Peak ~110 VGPR -> 4 waves/SIMD. __launch_bounds__(256,4) pins the tier;
// sched_barrier(0) keeps head loads out of phase 1.
// z made wave-uniform (lane=zp, wave id = z offset) so x0 is a broadcast.

#define ZD 64
#define BD 2048
#define NPAIR (ZD * ZD)   // 4096
#define BCHUNK 8

#define LOG2E 1.4426950408889634f
#define LN2   0.6931471805599453f

__device__ __forceinline__ void ld4(const float* __restrict__ p, float* d) {
    float4 v = *reinterpret_cast<const float4*>(p);
    d[0] = v.x; d[1] = v.y; d[2] = v.z; d[3] = v.w;
}

__device__ __forceinline__ float fast_exp(float x) {
    return __builtin_amdgcn_exp2f(x * LOG2E);
}

__device__ __forceinline__ float fast_tanh(float x) {
    // tanh(x) = (e^2x - 1) / (e^2x + 1); clamp so exp2 can't overflow
    float y = fminf(fmaxf(x, -9.0f), 9.0f);
    float t = __builtin_amdgcn_exp2f(y * (2.0f * LOG2E));
    return (t - 1.0f) * __builtin_amdgcn_rcpf(t + 1.0f);
}

__device__ __forceinline__ void layernorm4(float* h, const float* g, const float* be) {
    float m = (h[0] + h[1] + h[2] + h[3]) * 0.25f;
    float d0 = h[0] - m, d1 = h[1] - m, d2 = h[2] - m, d3 = h[3] - m;
    float v = (d0 * d0 + d1 * d1 + d2 * d2 + d3 * d3) * 0.25f;
    float rs = rsqrtf(v + 1e-5f);
    h[0] = d0 * rs * g[0] + be[0];
    h[1] = d1 * rs * g[1] + be[1];
    h[2] = d2 * rs * g[2] + be[2];
    h[3] = d3 * rs * g[3] + be[3];
}

__global__ __launch_bounds__(256, 4) void net_kernel(
    const float* __restrict__ nt,
    const float* __restrict__ W1,  const float* __restrict__ b1,
    const float* __restrict__ g1,  const float* __restrict__ be1,
    const float* __restrict__ W2,  const float* __restrict__ b2,
    const float* __restrict__ g2,  const float* __restrict__ be2,
    const float* __restrict__ Wpi, const float* __restrict__ bpi,
    const float* __restrict__ Wxi, const float* __restrict__ bxi,
    float* __restrict__ out)
{
    // lane = zp; wave id selects z within a 4-z group; blockIdx = (b-slice, z-group)
    const int lane = threadIdx.x & 63;
    const int wid  = threadIdx.x >> 6;
    const int zg   = blockIdx.x & 15;              // 16 z-groups of 4
    const int b0   = (blockIdx.x >> 4) * BCHUNK;   // 256 b-slices of 8
    const int z    = zg * 4 + wid;                 // wave-uniform
    const int zp   = lane;
    const int p    = z * ZD + zp;

    // ================= phase 1: trunk (2->4 tanh LN, 4->4 tanh LN) ==========
    float w1a[4], w1b[4], b1v[4], g1v[4], e1v[4];
    ld4(W1 + p * 8,     w1a);
    ld4(W1 + p * 8 + 4, w1b);
    ld4(b1  + p * 4, b1v);
    ld4(g1  + p * 4, g1v);
    ld4(be1 + p * 4, e1v);

    float w2v[16], b2v[4], g2v[4], e2v[4];
    #pragma unroll
    for (int i = 0; i < 4; ++i) ld4(W2 + p * 16 + i * 4, w2v + i * 4);
    ld4(b2  + p * 4, b2v);
    ld4(g2  + p * 4, g2v);
    ld4(be2 + p * 4, e2v);

    float h2s[BCHUNK][4];
    #pragma unroll
    for (int bi = 0; bi < BCHUNK; ++bi) {
        const int b = b0 + bi;
        const float x0 = nt[b * ZD + z];    // wave-uniform broadcast
        const float x1 = nt[b * ZD + zp];   // coalesced

        float h[4];
        #pragma unroll
        for (int i = 0; i < 4; ++i)
            h[i] = fast_tanh(fmaf(x0, w1a[i], fmaf(x1, w1b[i], b1v[i])));
        layernorm4(h, g1v, e1v);

        float h2[4];
        #pragma unroll
        for (int k = 0; k < 4; ++k) {
            float a = b2v[k];
            #pragma unroll
            for (int i = 0; i < 4; ++i) a = fmaf(h[i], w2v[i * 4 + k], a);
            h2[k] = fast_tanh(a);
        }
        layernorm4(h2, g2v, e2v);
        #pragma unroll
        for (int k = 0; k < 4; ++k) h2s[bi][k] = h2[k];
    }

    // keep head-weight loads out of phase 1 (would re-inflate live range)
    __builtin_amdgcn_sched_barrier(0);

    // ================= phase 2: heads + softmax/sigmoid + stores ============
    float wpv[16], bpv[4], wxv[16], bxv[4];
    #pragma unroll
    for (int i = 0; i < 4; ++i) {
        ld4(Wpi + p * 16 + i * 4, wpv + i * 4);
        ld4(Wxi + p * 16 + i * 4, wxv + i * 4);
    }
    ld4(bpi + p * 4, bpv);
    ld4(bxi + p * 4, bxv);

    const size_t OFF = (size_t)BD * NPAIR * 4;

    #pragma unroll
    for (int bi = 0; bi < BCHUNK; ++bi) {
        const int b = b0 + bi;

        float l[4], q[4];
        #pragma unroll
        for (int o = 0; o < 4; ++o) { l[o] = bpv[o]; q[o] = bxv[o]; }
        #pragma unroll
        for (int k = 0; k < 4; ++k) {
            const float hk = h2s[bi][k];
            #pragma unroll
            for (int o = 0; o < 4; ++o) {
                l[o] = fmaf(hk, wpv[k * 4 + o], l[o]);
                q[o] = fmaf(hk, wxv[k * 4 + o], q[o]);
            }
        }

        float mx = fmaxf(fmaxf(l[0], l[1]), fmaxf(l[2], l[3]));
        float e[4], s = 0.0f;
        #pragma unroll
        for (int o = 0; o < 4; ++o) { e[o] = fast_exp(l[o] - mx); s += e[o]; }
        float inv_s = __builtin_amdgcn_rcpf(s);
        float ls = __builtin_amdgcn_logf(s) * LN2;

        float4 ppi, plp, pxi;
        ppi.x = e[0] * inv_s; ppi.y = e[1] * inv_s;
        ppi.z = e[2] * inv_s; ppi.w = e[3] * inv_s;
        plp.x = (l[0] - mx) - ls; plp.y = (l[1] - mx) - ls;
        plp.z = (l[2] - mx) - ls; plp.w = (l[3] - mx) - ls;
        pxi.x = __builtin_amdgcn_rcpf(1.0f + fast_exp(-q[0]));
        pxi.y = __builtin_amdgcn_rcpf(1.0f + fast_exp(-q[1]));
        pxi.z = __builtin_amdgcn_rcpf(1.0f + fast_exp(-q[2]));
        pxi.w = __builtin_amdgcn_rcpf(1.0f + fast_exp(-q[3]));

        const size_t gi = ((size_t)b * NPAIR + p) * 4;
        *reinterpret_cast<float4*>(out + gi)           = ppi;
        *reinterpret_cast<float4*>(out + OFF + gi)     = plp;
        *reinterpret_cast<float4*>(out + 2 * OFF + gi) = pxi;
    }
}

extern "C" void kernel_launch(void* const* d_in, const int* in_sizes, int n_in,
                              void* d_out, int out_size, void* d_ws, size_t ws_size,
                              hipStream_t stream) {
    const float* nt  = (const float*)d_in[0];
    const float* W1  = (const float*)d_in[1];
    const float* b1  = (const float*)d_in[2];
    const float* g1  = (const float*)d_in[3];
    const float* be1 = (const float*)d_in[4];
    const float* W2  = (const float*)d_in[5];
    const float* b2  = (const float*)d_in[6];
    const float* g2  = (const float*)d_in[7];
    const float* be2 = (const float*)d_in[8];
    const float* Wpi = (const float*)d_in[9];
    const float* bpi = (const float*)d_in[10];
    const float* Wxi = (const float*)d_in[11];
    const float* bxi = (const float*)d_in[12];
    float* out = (float*)d_out;

    // 16 z-groups x 256 b-slices = 4096 blocks x 256 threads, 8 outputs/thread
    dim3 grid(16 * (BD / BCHUNK)), block(256);
    net_kernel<<<grid, block, 0, stream>>>(nt, W1, b1, g1, be1, W2, b2, g2, be2,
                                           Wpi, bpi, Wxi, bxi, out);
}